// Round 6
// baseline (8836.559 us; speedup 1.0000x reference)
//
#include <hip/hip_runtime.h>

#define NB 4096
#define ND 64
#define NH 256
#define NT 50
#define ROWS 8
#define THREADS 512
#define GRID (NB / ROWS)   // 512 blocks -> exactly 2 per CU

// yi layout: [ROWS][2 halves][36] -> halves 36 floats (144B) apart, so the
// two half-wave broadcast b128 reads in GEMM1 hit disjoint bank quads.
#define YIS 72   // yi row stride (floats) = 2*36
#define ZS  260  // z row stride (floats)

__device__ __forceinline__ float fast_tanh(float x) {
  // tanh(x) = 1 - 2/(exp(2x)+1); safe at +-inf
  float e = __expf(2.0f * x);
  return 1.0f - 2.0f * __builtin_amdgcn_rcpf(e + 1.0f);
}

// Attribute model (validated rounds 1-5 on this kernel):
//   - waves_per_eu MAX sets the RA register budget (512/max); max=4 -> 128
//     VGPR cap, our demand ~112 fits -> no spill (round 5: FETCH dropped
//     1000x when max=4 took effect).
//   - waves_per_eu MIN bounds the achieved occupancy (r1:min1->12%,
//     r3/r4:min4->45-47%, r5:min2->24%). Grid supplies 2 blocks/CU = 4
//     waves/EU, so declare min=4 to actually get them.
extern "C" __global__
__attribute__((amdgpu_flat_work_group_size(THREADS, THREADS)))
__attribute__((amdgpu_waves_per_eu(4, 4)))
void ode_kernel(const float* __restrict__ y0,
                const float* __restrict__ tt,
                const float* __restrict__ W1,
                const float* __restrict__ b1,
                const float* __restrict__ W2,
                const float* __restrict__ b2,
                float* __restrict__ out)
{
  __shared__ float sYI[ROWS * YIS];        // 576 floats
  __shared__ float sZ[ROWS * ZS];          // 2080 floats
  __shared__ float sRed[8 * ROWS * ND];    // 4096 floats (16 KB)

  const int tid = threadIdx.x;
  // GEMM1 role: hidden column j1, d-half dh
  const int j1 = tid >> 1;
  const int dh = tid & 1;
  // GEMM2/state role: wave id = state row = j-chunk; d = dim
  const int wv = tid >> 6;
  const int d  = tid & 63;
  const int row = (int)blockIdx.x * ROWS + wv;

  // W1 slice in registers: W1[dh*32+dd][j1]
  float w1c[32];
#pragma unroll
  for (int dd = 0; dd < 32; ++dd) w1c[dd] = W1[(dh * 32 + dd) * NH + j1];
  const float b1j = b1[j1];

  // W2 slice in registers: W2[wv*32+jj][d]  (W2 never goes to LDS)
  float w2r[32];
#pragma unroll
  for (int jj = 0; jj < 32; ++jj) w2r[jj] = W2[(wv * 32 + jj) * ND + d];
  const float b2d = b2[d];

  // scalar state: y[row][d], exactly one owner per element
  float y = y0[row * ND + d];
  out[row * ND + d] = y;

  // yi write slot: row wv, half (d>>5), lane (d&31)
  const int yi_woff = wv * YIS + (d >> 5) * 36 + (d & 31);

  // f(yi) = tanh(yi @ W1 + b1) @ W2 + b2, scalar slice per thread.
  // Schedule: write yi | B_a | GEMM1, write z | B_b | GEMM2, write partials |
  //           B_c | reduce.
  auto feval = [&](float yiv) -> float {
    sYI[yi_woff] = yiv;
    __syncthreads();                      // B_a: yi visible; z/sRed writable

    // ---- GEMM1: z[j1][r] partial over d in [dh*32, dh*32+32) ----
    float z[ROWS];
#pragma unroll
    for (int r = 0; r < ROWS; ++r) z[r] = dh ? 0.0f : b1j;
#pragma unroll
    for (int db = 0; db < 8; ++db) {
      const float wa = w1c[db * 4 + 0];
      const float wb = w1c[db * 4 + 1];
      const float wc = w1c[db * 4 + 2];
      const float wd = w1c[db * 4 + 3];
#pragma unroll
      for (int r = 0; r < ROWS; ++r) {
        const float4 a = *(const float4*)&sYI[r * YIS + dh * 36 + db * 4];
        z[r] = fmaf(a.x, wa, z[r]);
        z[r] = fmaf(a.y, wb, z[r]);
        z[r] = fmaf(a.z, wc, z[r]);
        z[r] = fmaf(a.w, wd, z[r]);
      }
    }
    // combine the two d-halves (lane pairs); deterministic (a+b==b+a)
#pragma unroll
    for (int r = 0; r < ROWS; ++r) z[r] += __shfl_xor(z[r], 1, 64);
    // dh lane owns rows dh*4..dh*4+3: tanh + write (2-way bank alias = free)
#pragma unroll
    for (int r2 = 0; r2 < 4; ++r2) {
      const int r = dh * 4 + r2;
      sZ[r * ZS + j1] = fast_tanh(z[r]);
    }
    __syncthreads();                      // B_b: z visible

    // ---- GEMM2: partial o[r][d] over j-chunk wv (W2 in registers,
    //      z reads are full-wave uniform broadcasts) ----
    float p[ROWS];
#pragma unroll
    for (int r = 0; r < ROWS; ++r) p[r] = 0.0f;
    const float* __restrict__ zb = sZ + wv * 32;
#pragma unroll
    for (int jq = 0; jq < 8; ++jq) {
      const float wa = w2r[jq * 4 + 0];
      const float wb = w2r[jq * 4 + 1];
      const float wc = w2r[jq * 4 + 2];
      const float wd = w2r[jq * 4 + 3];
#pragma unroll
      for (int r = 0; r < ROWS; ++r) {
        const float4 zv = *(const float4*)&zb[r * ZS + jq * 4];
        p[r] = fmaf(zv.x, wa, p[r]);
        p[r] = fmaf(zv.y, wb, p[r]);
        p[r] = fmaf(zv.z, wc, p[r]);
        p[r] = fmaf(zv.w, wd, p[r]);
      }
    }
#pragma unroll
    for (int r = 0; r < ROWS; ++r) sRed[(wv * ROWS + r) * ND + d] = p[r];
    __syncthreads();                      // B_c: partials visible

    // reduce 8 j-chunks for own (row=wv, d); fixed order -> deterministic
    float o = b2d;
#pragma unroll
    for (int c = 0; c < 8; ++c) o += sRed[(c * ROWS + wv) * ND + d];
    return o;
  };

  // Dormand-Prince 5(4) tableau (5th-order solution row)
  const float A10 = (float)(1.0 / 5.0);
  const float A20 = (float)(3.0 / 40.0),      A21 = (float)(9.0 / 40.0);
  const float A30 = (float)(44.0 / 45.0),     A31 = (float)(-56.0 / 15.0),
              A32 = (float)(32.0 / 9.0);
  const float A40 = (float)(19372.0 / 6561.0), A41 = (float)(-25360.0 / 2187.0),
              A42 = (float)(64448.0 / 6561.0), A43 = (float)(-212.0 / 729.0);
  const float A50 = (float)(9017.0 / 3168.0),  A51 = (float)(-355.0 / 33.0),
              A52 = (float)(46732.0 / 5247.0), A53 = (float)(49.0 / 176.0),
              A54 = (float)(-5103.0 / 18656.0);
  const float B0 = (float)(35.0 / 384.0),      B2 = (float)(500.0 / 1113.0),
              B3 = (float)(125.0 / 192.0),     B4 = (float)(-2187.0 / 6784.0),
              B5 = (float)(11.0 / 84.0);

  for (int ti = 0; ti < NT - 1; ++ti) {
    const float dt = (tt[ti + 1] - tt[ti]) * 0.25f;  // /SUBSTEPS, exact pow2
    for (int ss = 0; ss < 4; ++ss) {
      const float k0 = feval(y);

      float yi = fmaf(dt * A10, k0, y);
      const float k1 = feval(yi);

      yi = y;
      yi = fmaf(dt * A20, k0, yi); yi = fmaf(dt * A21, k1, yi);
      const float k2 = feval(yi);

      yi = y;
      yi = fmaf(dt * A30, k0, yi); yi = fmaf(dt * A31, k1, yi);
      yi = fmaf(dt * A32, k2, yi);
      const float k3 = feval(yi);

      yi = y;
      yi = fmaf(dt * A40, k0, yi); yi = fmaf(dt * A41, k1, yi);
      yi = fmaf(dt * A42, k2, yi); yi = fmaf(dt * A43, k3, yi);
      const float k4 = feval(yi);

      yi = y;
      yi = fmaf(dt * A50, k0, yi); yi = fmaf(dt * A51, k1, yi);
      yi = fmaf(dt * A52, k2, yi); yi = fmaf(dt * A53, k3, yi);
      yi = fmaf(dt * A54, k4, yi);
      const float k5 = feval(yi);

      // y_new = y + dt*(B0*k0 + B2*k2 + B3*k3 + B4*k4 + B5*k5)   (B1 = 0)
      y = fmaf(dt * B0, k0, y);
      y = fmaf(dt * B2, k2, y);
      y = fmaf(dt * B3, k3, y);
      y = fmaf(dt * B4, k4, y);
      y = fmaf(dt * B5, k5, y);
    }
    out[(size_t)(ti + 1) * NB * ND + row * ND + d] = y;
  }
}

extern "C" void kernel_launch(void* const* d_in, const int* in_sizes, int n_in,
                              void* d_out, int out_size, void* d_ws, size_t ws_size,
                              hipStream_t stream) {
  const float* y0 = (const float*)d_in[0];
  const float* tt = (const float*)d_in[1];
  const float* W1 = (const float*)d_in[2];
  const float* b1 = (const float*)d_in[3];
  const float* W2 = (const float*)d_in[4];
  const float* b2 = (const float*)d_in[5];
  float* out = (float*)d_out;

  hipLaunchKernelGGL(ode_kernel, dim3(GRID), dim3(THREADS), 0, stream,
                     y0, tt, W1, b1, W2, b2, out);
}